// Round 16
// baseline (1076.835 us; speedup 1.0000x reference)
//
#include <hip/hip_runtime.h>

typedef _Float16 f16;
typedef _Float16 f16x4 __attribute__((ext_vector_type(4)));
typedef _Float16 f16x8 __attribute__((ext_vector_type(8)));
typedef float f32x4 __attribute__((ext_vector_type(4)));
typedef int i32x4 __attribute__((ext_vector_type(4)));

#define TLEN 2048
#define TPAD 2050           // gates3 time extent (2 pad steps for prefetch)
#define NCOL 640            // 160 units x 4 gates, col = u*4 + G
#define GSTEP (16 * NCOL)   // f16 elements per timestep in gates3 [t][b][col]
#define SPITCH 1100         // LDS image pitch: 16B-aligned, <=2-way bank alias
#define NPROD 240           // producer blocks (bid 16..255)
#define K1 1.4426950408889634f
#define K2 2.8853900817779268f

// ---------------------------------------------------------------------------
// Scan step (i8 MFMA; hot loop bit-identical to r14/r15's proven version).
// ---------------------------------------------------------------------------
__device__ __forceinline__ void lstm_stepQ(
    int t, int cur, f16x4& pfu, f16x4& pfc, const f16*& pLoad,
    const i32x4 (&afrag)[5][3], const f32x4& scv,
    signed char* hqs, f16* hfs, float& cst,
    int grp, int sel, bool wr, int u)
{
    // 1) Issue next-next-step gates load first (longest latency).
    const f16x4 pnew = *(const f16x4*)pLoad;
    pLoad += GSTEP;

    // 2) B-fragment reads: 3 x b128 of quantized h (broadcast, conflict-free).
    const signed char* hr = hqs + cur * 192 + grp * 16;
    i32x4 bf[3];
    #pragma unroll
    for (int kt = 0; kt < 3; ++kt)
        bf[kt] = *(const i32x4*)(hr + kt * 64);

    // 3) In the read shadow: convert this step's unit-gates (f16->f32).
    float gx0 = (float)pfu[0], gx1 = (float)pfu[1];
    float gx2 = (float)pfu[2], gx3 = (float)pfu[3];
    pfc = pnew;

    // 4) i8 MFMA: 5 tiles x 3 kt, integer C-init 0.
    const i32x4 zc = {0, 0, 0, 0};
    i32x4 acc[5];
    #pragma unroll
    for (int i = 0; i < 5; ++i)
        acc[i] = __builtin_amdgcn_mfma_i32_16x16x64_i8(afrag[i][0], bf[0], zc, 0, 0, 0);
    #pragma unroll
    for (int kt = 1; kt < 3; ++kt)
        #pragma unroll
        for (int i = 0; i < 5; ++i)
            acc[i] = __builtin_amdgcn_mfma_i32_16x16x64_i8(afrag[i][kt], bf[kt], acc[i], 0, 0, 0);

    // 5) Select this lane's tile.
    int s0 = acc[0][0], s1 = acc[0][1], s2 = acc[0][2], s3 = acc[0][3];
    #pragma unroll
    for (int i = 1; i < 5; ++i) {
        const bool p = (sel == i);
        s0 = p ? acc[i][0] : s0;
        s1 = p ? acc[i][1] : s1;
        s2 = p ? acc[i][2] : s2;
        s3 = p ? acc[i][3] : s3;
    }

    // 6) Dequant + add gates_x (scv carries gate prescale/sign).
    const float g0 = fmaf((float)s0, scv[0], gx0);
    const float g1 = fmaf((float)s1, scv[1], gx1);
    const float g2 = fmaf((float)s2, scv[2], gx2);
    const float g3 = fmaf((float)s3, scv[3], gx3);

    // 7) Shared-denominator activation: 5 exp2 + 3 rcp; all paths finite.
    const float ei = __builtin_amdgcn_exp2f(g0);                // e^{-i}
    const float ef = __builtin_amdgcn_exp2f(g1);                // e^{-f}
    const float eg = __builtin_amdgcn_exp2f(fminf(g2, 38.f));   // e^{2g}
    const float eo = __builtin_amdgcn_exp2f(g3);                // e^{-o}
    const float dig = (1.f + ei) * (eg + 1.f);
    const float c = cst * __builtin_amdgcn_rcpf(1.f + ef)
                  + (eg - 1.f) * __builtin_amdgcn_rcpf(dig);
    cst = c;
    const float ec = __builtin_amdgcn_exp2f(fminf(K2 * c, 80.f));
    const float h = (ec - 1.f) * __builtin_amdgcn_rcpf((1.f + eo) * (ec + 1.f));

    // 8) Quantize + write h (i8); f16 copy only on the last step.
    if (wr) hqs[(cur ^ 1) * 192 + u] = (signed char)(int)rintf(127.f * h);
    if (t == TLEN - 1 && wr) hfs[u] = (f16)h;

    // 9) Drain LDS ops only; ONE raw barrier per step (vmcnt stays hot).
    asm volatile("s_waitcnt lgkmcnt(0)" ::: "memory");
    __builtin_amdgcn_s_barrier();
    __builtin_amdgcn_sched_barrier(0);
}

// ---------------------------------------------------------------------------
// MEGA kernel, single launch, ONE coarse sync point.
//   blocks 16..255 (240 producers): 8-9 contiguous timesteps each
//     (stage->conv->gates GEMM, r15's proven body); after ALL their stores:
//     __threadfence + one agent-release fetch_add on ctr.
//   blocks 0..15 (scan): self-init (rowmax + i8 quant -- overlaps producer
//     time), then ONE acquire-poll until ctr == 240 (single cache
//     invalidate, before any gates3 read), then the unmodified r15 hot
//     loop with zero mid-loop sync (vmcnt never drained).
// Deadlock-free: producers wait on nobody; 256 blocks = 256 CUs.
// ---------------------------------------------------------------------------
__global__ __launch_bounds__(512, 1) void mega(
    const float* __restrict__ inp, const float* __restrict__ cw,
    const float* __restrict__ cb,
    const float* __restrict__ w_ih, const float* __restrict__ b_ih,
    const float* __restrict__ b_hh, const float* __restrict__ w_hh,
    const float* __restrict__ last_w, const float* __restrict__ last_b,
    f16* __restrict__ gates3, int* __restrict__ ctr, float* __restrict__ out)
{
    const int bid = blockIdx.x;
    const int tid = threadIdx.x, w = tid >> 6, lane = tid & 63;
    const int col = lane & 15, grp = lane >> 4;

    if (bid >= 16) {
        // ------------------------------ producer ------------------------------
        __shared__ __align__(16) float s_in[16][SPITCH];   // 70.4 KB
        __shared__ __align__(16) f16 s_y[16][168];         // 5.4 KB
        __shared__ float s_w[612];
        for (int i = tid; i < 612; i += 512) s_w[i] = cw[i];

        // self-init: w_ih fragments + bias (identical math to r15)
        f16x8 bfr[5][5];
        float bb[5];
        #pragma unroll
        for (int i = 0; i < 5; ++i) {
            const int colg = (w * 5 + i) * 16 + col;
            const int u = colg >> 2, G = colg & 3;
            const float sc = (G == 2) ? K2 : -K1;
            const bool valid = (u < 150);
            const int row = valid ? G * 150 + u : 0;
            #pragma unroll
            for (int kt = 0; kt < 5; ++kt) {
                const int k0 = kt * 32 + grp * 8;
                f16x8 v;
                #pragma unroll
                for (int e = 0; e < 8; ++e) v[e] = (f16)0.f;
                if (valid && k0 < 144) {
                    const float* p = w_ih + (size_t)row * 144 + k0;
                    #pragma unroll
                    for (int e = 0; e < 8; ++e) v[e] = (f16)(p[e] * sc);
                }
                bfr[i][kt] = v;
            }
            bb[i] = valid ? (b_ih[row] + b_hh[row]) * sc : 0.f;
        }

        // conv role: cb_b = batch, unit -> (oc, oy)
        const int cb_b = tid & 15, unit = tid >> 4;
        const int oc = unit / 6, oy = unit % 6;
        const float cbias = (unit < 24) ? cb[oc] : 0.f;
        __syncthreads();

        // balanced contiguous ranges: 128 producers x 9 t + 112 x 8 t = 2048
        const int idx = bid - 16;
        const int tbeg = (idx < 128) ? idx * 9 : 1152 + (idx - 128) * 8;
        const int tcnt = (idx < 128) ? 9 : 8;

        for (int tl = 0; tl < tcnt; ++tl) {
            const int t = tbeg + tl;
            __syncthreads();   // guard s_in restage + s_y reuse
            {   // stage 16 images, float4 (32 threads per image, coalesced)
                const int si = tid >> 5, l2 = tid & 31;
                const float4* ip =
                    (const float4*)(inp + ((size_t)si * TLEN + t) * 1088);
                for (int k = l2; k < 272; k += 32)
                    *(float4*)(&s_in[si][k * 4]) = ip[k];
            }
            __syncthreads();
            if (unit < 24) {
                const float* wp = s_w + oc * 153;
                float acc[6] = {cbias, cbias, cbias, cbias, cbias, cbias};
                #pragma unroll 1
                for (int ic = 0; ic < 17; ++ic) {
                    #pragma unroll
                    for (int ky = 0; ky < 3; ++ky) {
                        const float* r = &s_in[cb_b][ic * 64 + (oy + ky) * 8];
                        const float4 f0 = *(const float4*)r;
                        const float4 f1 = *(const float4*)(r + 4);
                        const float w0 = wp[ic * 9 + ky * 3 + 0];
                        const float w1 = wp[ic * 9 + ky * 3 + 1];
                        const float w2 = wp[ic * 9 + ky * 3 + 2];
                        acc[0] += f0.x * w0 + f0.y * w1 + f0.z * w2;
                        acc[1] += f0.y * w0 + f0.z * w1 + f0.w * w2;
                        acc[2] += f0.z * w0 + f0.w * w1 + f1.x * w2;
                        acc[3] += f0.w * w0 + f1.x * w1 + f1.y * w2;
                        acc[4] += f1.x * w0 + f1.y * w1 + f1.z * w2;
                        acc[5] += f1.y * w0 + f1.z * w1 + f1.w * w2;
                    }
                }
                #pragma unroll
                for (int ox = 0; ox < 6; ++ox)
                    s_y[cb_b][oc * 36 + oy * 6 + ox] = (f16)fmaxf(acc[ox], 0.f);
            } else if (unit == 24) {
                #pragma unroll
                for (int k = 0; k < 16; ++k) s_y[cb_b][144 + k] = (f16)0.f;
            }
            __syncthreads();
            // gates GEMM for this timestep (A from LDS s_y, B resident)
            f16x8 a[5];
            #pragma unroll
            for (int kt = 0; kt < 5; ++kt)
                a[kt] = *(const f16x8*)(&s_y[col][kt * 32 + grp * 8]);
            #pragma unroll
            for (int i = 0; i < 5; ++i) {
                f32x4 acc = {0.f, 0.f, 0.f, 0.f};
                #pragma unroll
                for (int kt = 0; kt < 5; ++kt)
                    acc = __builtin_amdgcn_mfma_f32_16x16x32_f16(a[kt], bfr[i][kt], acc, 0, 0, 0);
                const int colg = (w * 5 + i) * 16 + col;
                #pragma unroll
                for (int r = 0; r < 4; ++r)
                    gates3[((size_t)(t * 16 + grp * 4 + r)) * NCOL + colg] =
                        (f16)(acc[r] + bb[i]);
            }
        }

        __threadfence();       // each thread's stores agent-visible
        __syncthreads();       // all threads' fences done
        if (tid == 0)
            __hip_atomic_fetch_add(ctr, 1, __ATOMIC_RELEASE,
                                   __HIP_MEMORY_SCOPE_AGENT);
        return;
    }

    // -------------------------------- scan --------------------------------
    __shared__ __align__(16) signed char hq[2 * 192];
    __shared__ __align__(16) f16 hf[160];
    __shared__ float s_rm[600];
    const int b = bid;
    const int sel = (col < 5) ? col : ((col < 10) ? col - 5 : ((col < 15) ? col - 10 : 0));
    const bool wr = (col < 5);
    const int u = 20 * w + 4 * sel + grp;

    for (int i = tid; i < 2 * 192; i += 512) hq[i] = 0;

    // cooperative per-row |max| of w_hh (overlaps producer time)
    for (int r = tid; r < 600; r += 512) {
        const float* p = w_hh + (size_t)r * 150;
        float m = 0.f;
        for (int k = 0; k < 150; k += 2) {
            m = fmaxf(m, fabsf(p[k]));
            m = fmaxf(m, fabsf(p[k + 1]));
        }
        s_rm[r] = m;
    }
    __syncthreads();

    // self-quantized i8 A-fragments (same k-map as r12-r15)
    i32x4 afrag[5][3];
    #pragma unroll
    for (int i = 0; i < 5; ++i) {
        const int colg = (5 * w + i) * 16 + col;
        const int uu = colg >> 2, G = colg & 3;
        const bool valid = (uu < 150);
        const int row = valid ? G * 150 + uu : 0;
        const float rm = s_rm[row];
        const float qs = (valid && rm > 0.f) ? 127.f / rm : 0.f;
        const float* p = w_hh + (size_t)row * 150;
        #pragma unroll
        for (int kt = 0; kt < 3; ++kt) {
            int wv[4] = {0, 0, 0, 0};
            #pragma unroll
            for (int byte = 0; byte < 16; ++byte) {
                const int k = kt * 64 + grp * 16 + byte;
                int q = 0;
                if (k < 150) q = (int)rintf(p[k] * qs);
                wv[byte >> 2] |= (q & 255) << ((byte & 3) * 8);
            }
            afrag[i][kt] = (i32x4){wv[0], wv[1], wv[2], wv[3]};
        }
    }
    f32x4 scv;
    {
        const bool vu = (u < 150);
        #pragma unroll
        for (int G = 0; G < 4; ++G) {
            const float sc = (G == 2) ? K2 : -K1;
            const int idx2 = vu ? G * 150 + u : 0;
            scv[G] = vu ? sc * s_rm[idx2] * (1.f / 16129.f) : 0.f;
        }
    }
    float cst = 0.f;
    __syncthreads();

    // ONE coarse sync: wait for all 240 producers (single acquire/invalidate
    // before any gates3 read; hot loop below has zero sync operations).
    if (tid == 0) {
        while (__hip_atomic_load(ctr, __ATOMIC_ACQUIRE,
                                 __HIP_MEMORY_SCOPE_AGENT) < NPROD)
            __builtin_amdgcn_s_sleep(8);
    }
    __syncthreads();

    const f16* gbu = gates3 + (size_t)b * NCOL + 80 * w + 16 * sel + 4 * grp;
    f16x4 pA = *(const f16x4*)(gbu);
    f16x4 pB = *(const f16x4*)(gbu + (size_t)1 * GSTEP);
    const f16* pLoad = gbu + (size_t)2 * GSTEP;

    #pragma unroll 1
    for (int tb = 0; tb < TLEN; tb += 2) {
        lstm_stepQ(tb,     0, pA, pA, pLoad, afrag, scv, hq, hf, cst, grp, sel, wr, u);
        lstm_stepQ(tb + 1, 1, pB, pB, pLoad, afrag, scv, hq, hf, cst, grp, sel, wr, u);
    }

    if (tid < 2) {
        float s = last_b[tid];
        for (int j = 0; j < 150; ++j)
            s += (float)hf[j] * last_w[tid * 150 + j];
        out[b * 2 + tid] = s;
    }
}

// ---------------------------------------------------------------------------
extern "C" void kernel_launch(void* const* d_in, const int* in_sizes, int n_in,
                              void* d_out, int out_size, void* d_ws, size_t ws_size,
                              hipStream_t stream) {
    const float* inp    = (const float*)d_in[0];
    const float* conv_w = (const float*)d_in[1];
    const float* conv_b = (const float*)d_in[2];
    const float* w_ih   = (const float*)d_in[3];
    const float* w_hh   = (const float*)d_in[4];
    const float* b_ih   = (const float*)d_in[5];
    const float* b_hh   = (const float*)d_in[6];
    const float* last_w = (const float*)d_in[7];
    const float* last_b = (const float*)d_in[8];
    float* out = (float*)d_out;

    char* ws = (char*)d_ws;
    f16* gates3 = (f16*)ws;                       // TPAD*16*640*2 = 41,984,000 B
    int* ctr    = (int*)(ws + 41984000);          // 64B-aligned

    hipMemsetAsync(ctr, 0, 64, stream);
    mega<<<256, 512, 0, stream>>>(inp, conv_w, conv_b, w_ih, b_ih, b_hh, w_hh,
                                  last_w, last_b, gates3, ctr, out);
}